// Round 7
// baseline (241.584 us; speedup 1.0000x reference)
//
#include <hip/hip_runtime.h>

// ExponentialUnitNorm, 3-kernel split scan; linear-float4 global access via
// double-buffered LDS staging (T14: issue stage k+1 loads BEFORE computing
// stage k; ONE barrier per stage). Tests/exploits the theory that the
// ~2.6 TB/s cap of all prior variants is the strided 512B-per-wave access
// pattern (DRAM page thrash), not MLP/occupancy/traffic (all ruled out).
//   pass1: stage 4 rows (962 float4, linear) -> LDS -> scan -> partials.
//   mid:   in-place partials -> chunk-entry states (proven R5 form).
//   pass2: strided float2 reads (L3-resident x), normalize into LDS,
//          linear float4 NT stores of out (out never re-read).
// NC=100 chunks (L=20), 1600 blocks, 30.8 KB LDS -> 5 blocks/CU.
// absmax floor 0.03125 = 1 bf16 ulp (bf16-quantized comparison).

#define ALPHA_F 0.99f
#define OMA_F   0.01f
#define EPS_F   1e-14f

typedef float f32x4 __attribute__((ext_vector_type(4)));

constexpr int Bn = 16;
constexpr int Tn = 2000;
constexpr int Fn = 481;
constexpr int NC = 100;          // chunks along T
constexpr int L  = Tn / NC;      // 20 rows per chunk
constexpr int ST = 4;            // rows per stage
constexpr int NST = L / ST;      // 5 stages
constexpr int RF  = 2 * Fn;      // floats per row = 962
constexpr int SF4 = ST * RF / 4; // 962 float4 per stage (stage is 16B-aligned)
constexpr int TL3 = SF4 - 3 * 256;  // 194 (4th load partial)
constexpr int MT = 25;           // mid tile
#define ALPHA_L 0.817906938f     // 0.99^20

__global__ __launch_bounds__(256) void eun_pass1(
    const float* __restrict__ x, float* __restrict__ part) {
  __shared__ f32x4 lds[2][SF4];  // 30784 B
  const int tid = threadIdx.x;
  const int c = blockIdx.x, b = blockIdx.y;

  const size_t base_f = ((size_t)b * Tn + (size_t)c * L) * RF;
  const f32x4* xb = (const f32x4*)(x + base_f);

  // prologue: stage 0 -> LDS buf 0
  f32x4 v[4];
#pragma unroll
  for (int j = 0; j < 3; ++j) v[j] = xb[tid + 256 * j];
  if (tid < TL3) v[3] = xb[tid + 256 * 3];
#pragma unroll
  for (int j = 0; j < 3; ++j) lds[0][tid + 256 * j] = v[j];
  if (tid < TL3) lds[0][tid + 256 * 3] = v[3];
  __syncthreads();

  const int f1 = tid, f2 = tid + 256;
  float s1 = 0.f, s2 = 0.f;
  int cur = 0;
  for (int st = 0; st < NST; ++st) {
    // (a) issue next-stage loads (latency hides under compute below)
    if (st + 1 < NST) {
      const f32x4* sb = xb + (size_t)(st + 1) * SF4;
#pragma unroll
      for (int j = 0; j < 3; ++j) v[j] = sb[tid + 256 * j];
      if (tid < TL3) v[3] = sb[tid + 256 * 3];
    }
    // (b) compute current stage from LDS (float2 reads, 2-way alias = free)
    const float2* l2 = (const float2*)lds[cur];
#pragma unroll
    for (int r = 0; r < ST; ++r) {
      float2 a = l2[r * Fn + f1];
      float m = sqrtf(fmaxf(fmaf(a.x, a.x, a.y * a.y), EPS_F));
      s1 = fmaf(ALPHA_F, s1, OMA_F * m);
      if (f2 < Fn) {
        float2 q = l2[r * Fn + f2];
        float m2 = sqrtf(fmaxf(fmaf(q.x, q.x, q.y * q.y), EPS_F));
        s2 = fmaf(ALPHA_F, s2, OMA_F * m2);
      }
    }
    // (c) write next stage into the other buffer (read at st-1 is long done)
    if (st + 1 < NST) {
#pragma unroll
      for (int j = 0; j < 3; ++j) lds[cur ^ 1][tid + 256 * j] = v[j];
      if (tid < TL3) lds[cur ^ 1][tid + 256 * 3] = v[3];
    }
    __syncthreads();  // one barrier per stage
    cur ^= 1;
  }
  float* pp = part + ((size_t)b * NC + c) * Fn;
  pp[f1] = s1;
  if (f2 < Fn) pp[f2] = s2;
}

// In-place: part[b,c,f] (chunk partial B_c) -> chunk-entry state S_c.
__global__ __launch_bounds__(256) void eun_mid(
    const float* __restrict__ init_state, float* __restrict__ part) {
  const int f = blockIdx.x * blockDim.x + threadIdx.x;
  if (f >= Fn) return;
  const int b = blockIdx.y;
  float* pp = part + (size_t)b * NC * Fn + f;
  float s = init_state[f];
  for (int c0 = 0; c0 < NC; c0 += MT) {
    float p[MT];
#pragma unroll
    for (int k = 0; k < MT; ++k) p[k] = pp[(size_t)(c0 + k) * Fn];
#pragma unroll
    for (int k = 0; k < MT; ++k) {
      pp[(size_t)(c0 + k) * Fn] = s;          // S_c over B_c, in place
      s = fmaf(s, ALPHA_L, p[k]);             // S_{c+1} = aL*S_c + B_c
    }
  }
}

__global__ __launch_bounds__(256) void eun_pass2(
    const float* __restrict__ x, const float* __restrict__ start,
    float* __restrict__ out) {
  __shared__ f32x4 lds[2][SF4];
  const int tid = threadIdx.x;
  const int c = blockIdx.x, b = blockIdx.y;

  const size_t base_f = ((size_t)b * Tn + (size_t)c * L) * RF;
  const int f1 = tid, f2 = tid + 256;
  const bool a2 = (f2 < Fn);

  float s1 = start[((size_t)b * NC + c) * Fn + f1];
  float s2 = a2 ? start[((size_t)b * NC + c) * Fn + f2] : 0.f;

  const float* xp1 = x + base_f + (size_t)f1 * 2;
  const float* xp2 = x + base_f + (size_t)f2 * 2;

  float2 av[ST], qv[ST], an[ST], qn[ST];
  // prologue: stage-0 strided loads (L3 hits; x warmed by pass1)
#pragma unroll
  for (int r = 0; r < ST; ++r) {
    av[r] = *(const float2*)(xp1 + (size_t)r * RF);
    if (a2) qv[r] = *(const float2*)(xp2 + (size_t)r * RF);
  }

  int cur = 0;
  for (int st = 0; st < NST; ++st) {
    // (a) issue next-stage loads
    if (st + 1 < NST) {
      const float* p1 = xp1 + (size_t)(st + 1) * ST * RF;
      const float* p2 = xp2 + (size_t)(st + 1) * ST * RF;
#pragma unroll
      for (int r = 0; r < ST; ++r) {
        an[r] = *(const float2*)(p1 + (size_t)r * RF);
        if (a2) qn[r] = *(const float2*)(p2 + (size_t)r * RF);
      }
    }
    // (b) scan + normalize current stage into LDS
    float2* l2 = (float2*)lds[cur];
#pragma unroll
    for (int r = 0; r < ST; ++r) {
      float m = sqrtf(fmaxf(fmaf(av[r].x, av[r].x, av[r].y * av[r].y), EPS_F));
      s1 = fmaf(ALPHA_F, s1, OMA_F * m);
      float inv1 = rsqrtf(s1);
      l2[r * Fn + f1] = make_float2(av[r].x * inv1, av[r].y * inv1);
      if (a2) {
        float m2 = sqrtf(fmaxf(fmaf(qv[r].x, qv[r].x, qv[r].y * qv[r].y), EPS_F));
        s2 = fmaf(ALPHA_F, s2, OMA_F * m2);
        float inv2 = rsqrtf(s2);
        l2[r * Fn + f2] = make_float2(qv[r].x * inv2, qv[r].y * inv2);
      }
    }
    __syncthreads();  // one barrier per stage
    // (c) linear float4 NT store of this stage
    f32x4* ob = (f32x4*)(out + base_f) + (size_t)st * SF4;
    const f32x4* ls = (const f32x4*)lds[cur];
#pragma unroll
    for (int j = 0; j < 3; ++j) {
      f32x4 o = ls[tid + 256 * j];
      __builtin_nontemporal_store(o, ob + tid + 256 * j);
    }
    if (tid < TL3) {
      f32x4 o = ls[tid + 256 * 3];
      __builtin_nontemporal_store(o, ob + tid + 256 * 3);
    }
    // rotate prefetched regs
#pragma unroll
    for (int r = 0; r < ST; ++r) { av[r] = an[r]; qv[r] = qn[r]; }
    cur ^= 1;
  }
}

extern "C" void kernel_launch(void* const* d_in, const int* in_sizes, int n_in,
                              void* d_out, int out_size, void* d_ws, size_t ws_size,
                              hipStream_t stream) {
  const float* x    = (const float*)d_in[0];
  const float* init = (const float*)d_in[1];
  float* out        = (float*)d_out;
  float* part       = (float*)d_ws;  // Bn*NC*Fn floats = 3.08 MB

  dim3 grid(NC, Bn);  // 100 x 16 = 1600 blocks
  eun_pass1<<<grid, dim3(256), 0, stream>>>(x, part);
  eun_mid<<<dim3((Fn + 255) / 256, Bn), dim3(256), 0, stream>>>(init, part);
  eun_pass2<<<grid, dim3(256), 0, stream>>>(x, part, out);
}